// Round 3
// baseline (371.896 us; speedup 1.0000x reference)
//
#include <hip/hip_runtime.h>

#define IN_FEATS 128
#define HIDDEN 32
#define TILE_NODES 64   // nodes staged per block

// ---------------------------------------------------------------------------
// Kernel 1: P[node][0:32] = embed[node] @ W1s.T ; P[node][32:64] = @ W1d.T
// Lane = output unit j (j<32: Ps[h=j], j>=32: Pd[h=j-32]). W1 row lives in
// 32 float4 VGPRs per lane. Nodes streamed from an LDS tile via broadcast
// ds_read_b128 (all lanes same address -> conflict-free). 4 nodes in flight
// per lane for FMA dep-chain cover. Stores are lane-contiguous (256 B/wave).
// ---------------------------------------------------------------------------
__global__ __launch_bounds__(256) void precompute_P(
    const float* __restrict__ embed,
    const float* __restrict__ W1,
    float* __restrict__ P,
    int n_nodes)
{
    __shared__ float e_lds[TILE_NODES * IN_FEATS];   // 32 KB
    const int t    = threadIdx.x;
    const int lane = t & 63;
    const int wave = t >> 6;
    const int node0 = blockIdx.x * TILE_NODES;

    // --- W1 row -> VGPRs (one-time, 32 KB table, L2-resident) ---
    const int table = lane >> 5;          // 0 = src half, 1 = dst half
    const int h     = lane & 31;
    const float* wrow = W1 + (size_t)h * (2 * IN_FEATS) + table * IN_FEATS;
    float4 w[32];
#pragma unroll
    for (int i = 0; i < 32; ++i)
        w[i] = *reinterpret_cast<const float4*>(wrow + i * 4);

    // --- Stage tile (linear 32 KB copy: rows are contiguous in embed) ---
    {
        const float4* gsrc = reinterpret_cast<const float4*>(embed + (size_t)node0 * IN_FEATS);
        float4* ldst = reinterpret_cast<float4*>(e_lds);
        const int valid_f4 = (n_nodes > node0)
                           ? min(TILE_NODES, n_nodes - node0) * (IN_FEATS / 4)
                           : 0;
#pragma unroll
        for (int i = 0; i < 8; ++i) {
            const int idx = i * 256 + t;           // 0..2047
            if (idx < valid_f4) ldst[idx] = gsrc[idx];
        }
    }
    __syncthreads();

    // --- Compute: each wave owns 16 nodes of the tile, 4 groups of 4 ---
#pragma unroll
    for (int g = 0; g < 4; ++g) {
        const int nl = wave * 16 + g * 4;          // local node base
        const float* e0 = e_lds + (nl + 0) * IN_FEATS;
        const float* e1 = e_lds + (nl + 1) * IN_FEATS;
        const float* e2 = e_lds + (nl + 2) * IN_FEATS;
        const float* e3 = e_lds + (nl + 3) * IN_FEATS;
        float acc0 = 0.f, acc1 = 0.f, acc2 = 0.f, acc3 = 0.f;
#pragma unroll
        for (int i = 0; i < 32; ++i) {
            const float4 a = *reinterpret_cast<const float4*>(e0 + i * 4);
            const float4 b = *reinterpret_cast<const float4*>(e1 + i * 4);
            const float4 c = *reinterpret_cast<const float4*>(e2 + i * 4);
            const float4 d = *reinterpret_cast<const float4*>(e3 + i * 4);
            const float4 wi = w[i];
            // interleaved: 4 independent chains, 4-instr spacing >= dep latency
            acc0 = fmaf(a.x, wi.x, acc0);
            acc1 = fmaf(b.x, wi.x, acc1);
            acc2 = fmaf(c.x, wi.x, acc2);
            acc3 = fmaf(d.x, wi.x, acc3);
            acc0 = fmaf(a.y, wi.y, acc0);
            acc1 = fmaf(b.y, wi.y, acc1);
            acc2 = fmaf(c.y, wi.y, acc2);
            acc3 = fmaf(d.y, wi.y, acc3);
            acc0 = fmaf(a.z, wi.z, acc0);
            acc1 = fmaf(b.z, wi.z, acc1);
            acc2 = fmaf(c.z, wi.z, acc2);
            acc3 = fmaf(d.z, wi.z, acc3);
            acc0 = fmaf(a.w, wi.w, acc0);
            acc1 = fmaf(b.w, wi.w, acc1);
            acc2 = fmaf(c.w, wi.w, acc2);
            acc3 = fmaf(d.w, wi.w, acc3);
        }
        const int n = node0 + nl;
        if (n + 0 < n_nodes) P[(size_t)(n + 0) * 64 + lane] = acc0;
        if (n + 1 < n_nodes) P[(size_t)(n + 1) * 64 + lane] = acc1;
        if (n + 2 < n_nodes) P[(size_t)(n + 2) * 64 + lane] = acc2;
        if (n + 3 < n_nodes) P[(size_t)(n + 3) * 64 + lane] = acc3;
    }
}

// ---------------------------------------------------------------------------
// Kernel 2: per-edge  logits = relu(P[s][0:32] + P[d][32:64] + b1) @ W2.T + b2
// One thread per edge; 16 float4 gathers from the 25.6 MB L3-resident table.
// ---------------------------------------------------------------------------
__global__ __launch_bounds__(256) void edge_classify(
    const int* __restrict__ src,
    const int* __restrict__ dst,
    const float* __restrict__ P,
    const float* __restrict__ b1,
    const float* __restrict__ W2,
    const float* __restrict__ b2,
    float* __restrict__ out,
    int n_edges)
{
    const int e = blockIdx.x * 256 + threadIdx.x;
    if (e >= n_edges) return;
    const int s = src[e];
    const int d = dst[e];
    const float4* ps = reinterpret_cast<const float4*>(P + (size_t)s * 64);
    const float4* pd = reinterpret_cast<const float4*>(P + (size_t)d * 64 + 32);

    float4 a[8], b[8];
#pragma unroll
    for (int q = 0; q < 8; ++q) { a[q] = ps[q]; b[q] = pd[q]; }

    float l0 = b2[0], l1 = b2[1];
#pragma unroll
    for (int q = 0; q < 8; ++q) {
        const float va[4] = {a[q].x, a[q].y, a[q].z, a[q].w};
        const float vb[4] = {b[q].x, b[q].y, b[q].z, b[q].w};
#pragma unroll
        for (int j = 0; j < 4; ++j) {
            const int k = q * 4 + j;
            float hval = va[j] + vb[j] + b1[k];
            hval = fmaxf(hval, 0.f);
            l0 = fmaf(hval, W2[k], l0);
            l1 = fmaf(hval, W2[HIDDEN + k], l1);
        }
    }
    *reinterpret_cast<float2*>(out + (size_t)e * 2) = make_float2(l0, l1);
}

// ---------------------------------------------------------------------------
// Fallback (only if workspace too small): direct per-edge computation.
// ---------------------------------------------------------------------------
__global__ __launch_bounds__(256) void edge_direct(
    const int* __restrict__ src, const int* __restrict__ dst,
    const float* __restrict__ embed,
    const float* __restrict__ W1, const float* __restrict__ b1,
    const float* __restrict__ W2, const float* __restrict__ b2,
    float* __restrict__ out, int n_edges)
{
    const int e = blockIdx.x * 256 + threadIdx.x;
    if (e >= n_edges) return;
    const int s = src[e], d = dst[e];
    const float* se = embed + (size_t)s * IN_FEATS;
    const float* de = embed + (size_t)d * IN_FEATS;

    float acc[HIDDEN];
#pragma unroll
    for (int hh = 0; hh < HIDDEN; ++hh) acc[hh] = b1[hh];

    for (int c = 0; c < 4; ++c) {
        float es[32], ed[32];
#pragma unroll
        for (int q = 0; q < 8; ++q) {
            const float4 v = *reinterpret_cast<const float4*>(se + c * 32 + q * 4);
            es[q*4+0] = v.x; es[q*4+1] = v.y; es[q*4+2] = v.z; es[q*4+3] = v.w;
            const float4 u = *reinterpret_cast<const float4*>(de + c * 32 + q * 4);
            ed[q*4+0] = u.x; ed[q*4+1] = u.y; ed[q*4+2] = u.z; ed[q*4+3] = u.w;
        }
#pragma unroll
        for (int hh = 0; hh < HIDDEN; ++hh) {
            float acch = acc[hh];
#pragma unroll
            for (int k = 0; k < 32; ++k) {
                acch = fmaf(es[k], W1[hh * 256 + c * 32 + k], acch);
                acch = fmaf(ed[k], W1[hh * 256 + 128 + c * 32 + k], acch);
            }
            acc[hh] = acch;
        }
    }

    float l0 = b2[0], l1 = b2[1];
#pragma unroll
    for (int hh = 0; hh < HIDDEN; ++hh) {
        const float hv = fmaxf(acc[hh], 0.f);
        l0 = fmaf(hv, W2[hh], l0);
        l1 = fmaf(hv, W2[HIDDEN + hh], l1);
    }
    *reinterpret_cast<float2*>(out + (size_t)e * 2) = make_float2(l0, l1);
}

extern "C" void kernel_launch(void* const* d_in, const int* in_sizes, int n_in,
                              void* d_out, int out_size, void* d_ws, size_t ws_size,
                              hipStream_t stream)
{
    const int*   src = (const int*)d_in[0];
    const int*   dst = (const int*)d_in[1];
    const float* emb = (const float*)d_in[2];
    const float* W1  = (const float*)d_in[3];
    const float* b1  = (const float*)d_in[4];
    const float* W2  = (const float*)d_in[5];
    const float* b2  = (const float*)d_in[6];
    float* out = (float*)d_out;

    const int n_edges = in_sizes[0];
    const int n_nodes = in_sizes[2] / IN_FEATS;

    const size_t need = (size_t)n_nodes * 64 * sizeof(float);
    const int nb_edges = (n_edges + 255) / 256;

    if (ws_size >= need) {
        float* P = (float*)d_ws;
        const int nb_nodes = (n_nodes + TILE_NODES - 1) / TILE_NODES;
        precompute_P<<<nb_nodes, 256, 0, stream>>>(emb, W1, P, n_nodes);
        edge_classify<<<nb_edges, 256, 0, stream>>>(src, dst, P, b1, W2, b2, out, n_edges);
    } else {
        edge_direct<<<nb_edges, 256, 0, stream>>>(src, dst, emb, W1, b1, W2, b2, out, n_edges);
    }
}

// Round 4
// 174.811 us; speedup vs baseline: 2.1274x; 2.1274x over previous
//
#include <hip/hip_runtime.h>

#define IN_FEATS 128
#define HIDDEN 32

// ---------------------------------------------------------------------------
// Kernel 1: P[n][0:32] = embed[n] @ W1s.T ; P[n][32:64] = embed[n] @ W1d.T
//
// Block = 256 threads = 4 waves; tile = 32 nodes.
//   wave -> (kh = wave&1: k-half, ng = wave>>1: node-group of 16)
//   lane -> output unit u (u<32: Ps row u, u>=32: Pd row u-32)
// Per-lane W = 64 floats (16 float4 = 64 VGPRs)  -- no spill (R3 lesson:
// 128-float W rows forced scratch spills, 770 MB of write traffic).
// e-loads are wave-uniform broadcast 16B requests (L1/L2-served, no LDS
// staging). K-halves combine via an 8 KB LDS partial buffer + one barrier.
// ---------------------------------------------------------------------------
__global__ __launch_bounds__(256) void precompute_P(
    const float* __restrict__ embed,
    const float* __restrict__ W1,
    float* __restrict__ P,
    int n_nodes)
{
    __shared__ float partial[2][16][64];   // [ng][node][unit] = 8 KB
    const int t    = threadIdx.x;
    const int lane = t & 63;
    const int wave = t >> 6;
    const int kh   = wave & 1;             // k-half this wave owns
    const int ng   = wave >> 1;            // node-group (16 nodes)
    const int node0 = blockIdx.x * 32 + ng * 16;

    // --- W half-row -> 64 VGPRs ---
    const int h   = lane & 31;
    const int tbl = lane >> 5;             // 0 = src half, 1 = dst half
    const float* wrow = W1 + (size_t)h * (2 * IN_FEATS) + tbl * IN_FEATS + kh * 64;
    float4 w[16];
#pragma unroll
    for (int i = 0; i < 16; ++i)
        w[i] = *reinterpret_cast<const float4*>(wrow + i * 4);

    float acc[4][4];                       // [group][node-in-group], static idx
#pragma unroll
    for (int g = 0; g < 4; ++g)
#pragma unroll
        for (int j = 0; j < 4; ++j) acc[g][j] = 0.f;

    const int last = (n_nodes > 0) ? (n_nodes - 1) : 0;

#pragma unroll
    for (int g = 0; g < 4; ++g) {
        const int nb = node0 + g * 4;
        // clamped pointers: always in-bounds; stores are guarded below
        const float4* e0 = reinterpret_cast<const float4*>(
            embed + (size_t)min(nb + 0, last) * IN_FEATS + kh * 64);
        const float4* e1 = reinterpret_cast<const float4*>(
            embed + (size_t)min(nb + 1, last) * IN_FEATS + kh * 64);
        const float4* e2 = reinterpret_cast<const float4*>(
            embed + (size_t)min(nb + 2, last) * IN_FEATS + kh * 64);
        const float4* e3 = reinterpret_cast<const float4*>(
            embed + (size_t)min(nb + 3, last) * IN_FEATS + kh * 64);
#pragma unroll
        for (int i = 0; i < 16; ++i) {
            const float4 a = e0[i];
            const float4 b = e1[i];
            const float4 c = e2[i];
            const float4 d = e3[i];
            const float4 wi = w[i];
            // 4 independent chains, 4-instr spacing >= FMA dep latency
            acc[g][0] = fmaf(a.x, wi.x, acc[g][0]);
            acc[g][1] = fmaf(b.x, wi.x, acc[g][1]);
            acc[g][2] = fmaf(c.x, wi.x, acc[g][2]);
            acc[g][3] = fmaf(d.x, wi.x, acc[g][3]);
            acc[g][0] = fmaf(a.y, wi.y, acc[g][0]);
            acc[g][1] = fmaf(b.y, wi.y, acc[g][1]);
            acc[g][2] = fmaf(c.y, wi.y, acc[g][2]);
            acc[g][3] = fmaf(d.y, wi.y, acc[g][3]);
            acc[g][0] = fmaf(a.z, wi.z, acc[g][0]);
            acc[g][1] = fmaf(b.z, wi.z, acc[g][1]);
            acc[g][2] = fmaf(c.z, wi.z, acc[g][2]);
            acc[g][3] = fmaf(d.z, wi.z, acc[g][3]);
            acc[g][0] = fmaf(a.w, wi.w, acc[g][0]);
            acc[g][1] = fmaf(b.w, wi.w, acc[g][1]);
            acc[g][2] = fmaf(c.w, wi.w, acc[g][2]);
            acc[g][3] = fmaf(d.w, wi.w, acc[g][3]);
        }
    }

    // --- combine k-halves: kh=0 -> LDS, kh=1 adds and stores ---
    if (kh == 0) {
#pragma unroll
        for (int g = 0; g < 4; ++g)
#pragma unroll
            for (int j = 0; j < 4; ++j)
                partial[ng][g * 4 + j][lane] = acc[g][j];
    }
    __syncthreads();
    if (kh == 1) {
#pragma unroll
        for (int g = 0; g < 4; ++g)
#pragma unroll
            for (int j = 0; j < 4; ++j) {
                const int n = node0 + g * 4 + j;
                if (n < n_nodes)
                    P[(size_t)n * 64 + lane] =
                        acc[g][j] + partial[ng][g * 4 + j][lane];
            }
    }
}

// ---------------------------------------------------------------------------
// Kernel 2: per-edge  logits = relu(P[s][0:32] + P[d][32:64] + b1) @ W2.T + b2
// One thread per edge; 16 float4 gathers from the 25.6 MB L2/L3-resident table.
// ---------------------------------------------------------------------------
__global__ __launch_bounds__(256) void edge_classify(
    const int* __restrict__ src,
    const int* __restrict__ dst,
    const float* __restrict__ P,
    const float* __restrict__ b1,
    const float* __restrict__ W2,
    const float* __restrict__ b2,
    float* __restrict__ out,
    int n_edges)
{
    const int e = blockIdx.x * 256 + threadIdx.x;
    if (e >= n_edges) return;
    const int s = src[e];
    const int d = dst[e];
    const float4* ps = reinterpret_cast<const float4*>(P + (size_t)s * 64);
    const float4* pd = reinterpret_cast<const float4*>(P + (size_t)d * 64 + 32);

    float4 a[8], b[8];
#pragma unroll
    for (int q = 0; q < 8; ++q) { a[q] = ps[q]; b[q] = pd[q]; }

    float l0 = b2[0], l1 = b2[1];
#pragma unroll
    for (int q = 0; q < 8; ++q) {
        const float va[4] = {a[q].x, a[q].y, a[q].z, a[q].w};
        const float vb[4] = {b[q].x, b[q].y, b[q].z, b[q].w};
#pragma unroll
        for (int j = 0; j < 4; ++j) {
            const int k = q * 4 + j;
            float hval = va[j] + vb[j] + b1[k];
            hval = fmaxf(hval, 0.f);
            l0 = fmaf(hval, W2[k], l0);
            l1 = fmaf(hval, W2[HIDDEN + k], l1);
        }
    }
    *reinterpret_cast<float2*>(out + (size_t)e * 2) = make_float2(l0, l1);
}

// ---------------------------------------------------------------------------
// Fallback (only if workspace too small): direct per-edge computation.
// ---------------------------------------------------------------------------
__global__ __launch_bounds__(256) void edge_direct(
    const int* __restrict__ src, const int* __restrict__ dst,
    const float* __restrict__ embed,
    const float* __restrict__ W1, const float* __restrict__ b1,
    const float* __restrict__ W2, const float* __restrict__ b2,
    float* __restrict__ out, int n_edges)
{
    const int e = blockIdx.x * 256 + threadIdx.x;
    if (e >= n_edges) return;
    const int s = src[e], d = dst[e];
    const float* se = embed + (size_t)s * IN_FEATS;
    const float* de = embed + (size_t)d * IN_FEATS;

    float acc[HIDDEN];
#pragma unroll
    for (int hh = 0; hh < HIDDEN; ++hh) acc[hh] = b1[hh];

    for (int c = 0; c < 4; ++c) {
        float es[32], ed[32];
#pragma unroll
        for (int q = 0; q < 8; ++q) {
            const float4 v = *reinterpret_cast<const float4*>(se + c * 32 + q * 4);
            es[q*4+0] = v.x; es[q*4+1] = v.y; es[q*4+2] = v.z; es[q*4+3] = v.w;
            const float4 u = *reinterpret_cast<const float4*>(de + c * 32 + q * 4);
            ed[q*4+0] = u.x; ed[q*4+1] = u.y; ed[q*4+2] = u.z; ed[q*4+3] = u.w;
        }
#pragma unroll
        for (int hh = 0; hh < HIDDEN; ++hh) {
            float acch = acc[hh];
#pragma unroll
            for (int k = 0; k < 32; ++k) {
                acch = fmaf(es[k], W1[hh * 256 + c * 32 + k], acch);
                acch = fmaf(ed[k], W1[hh * 256 + 128 + c * 32 + k], acch);
            }
            acc[hh] = acch;
        }
    }

    float l0 = b2[0], l1 = b2[1];
#pragma unroll
    for (int hh = 0; hh < HIDDEN; ++hh) {
        const float hv = fmaxf(acc[hh], 0.f);
        l0 = fmaf(hv, W2[hh], l0);
        l1 = fmaf(hv, W2[HIDDEN + hh], l1);
    }
    *reinterpret_cast<float2*>(out + (size_t)e * 2) = make_float2(l0, l1);
}

extern "C" void kernel_launch(void* const* d_in, const int* in_sizes, int n_in,
                              void* d_out, int out_size, void* d_ws, size_t ws_size,
                              hipStream_t stream)
{
    const int*   src = (const int*)d_in[0];
    const int*   dst = (const int*)d_in[1];
    const float* emb = (const float*)d_in[2];
    const float* W1  = (const float*)d_in[3];
    const float* b1  = (const float*)d_in[4];
    const float* W2  = (const float*)d_in[5];
    const float* b2  = (const float*)d_in[6];
    float* out = (float*)d_out;

    const int n_edges = in_sizes[0];
    const int n_nodes = in_sizes[2] / IN_FEATS;

    const size_t need = (size_t)n_nodes * 64 * sizeof(float);
    const int nb_edges = (n_edges + 255) / 256;

    if (ws_size >= need) {
        float* P = (float*)d_ws;
        const int nb_nodes = (n_nodes + 31) / 32;   // 32-node tiles
        precompute_P<<<nb_nodes, 256, 0, stream>>>(emb, W1, P, n_nodes);
        edge_classify<<<nb_edges, 256, 0, stream>>>(src, dst, P, b1, W2, b2, out, n_edges);
    } else {
        edge_direct<<<nb_edges, 256, 0, stream>>>(src, dst, emb, W1, b1, W2, b2, out, n_edges);
    }
}

// Round 5
// 90.266 us; speedup vs baseline: 4.1200x; 1.9366x over previous
//
#include <hip/hip_runtime.h>

#define IN_FEATS 128
#define HIDDEN 32

// ---------------------------------------------------------------------------
// Kernel 1: P[n][0:32] = embed[n] @ W1s.T ; P[n][32:64] = embed[n] @ W1d.T
//
// Block = 256 threads = 4 waves; tile = 32 nodes.
//   wave -> (kh = wave&1: k-half of 64, ng = wave>>1: node-group of 16)
//   lane -> output unit u (u<32: Ps row u, u>=32: Pd row u-32)
//
// R4 lesson: compiler rematerialized w[16] (VGPR_Count=40) -> per-iteration
// 64-way-scattered W gathers + latency-exposed e loads -> VALUBusy 14%.
// Fixes: (1) asm-pin W into VGPRs (remat impossible), (2) readfirstlane the
// wave-uniform e row offsets -> s_load on the scalar pipe (imm-offset folded),
// leaving the VALU stream as pure FMA with 16 independent chains.
// ---------------------------------------------------------------------------
__global__ __launch_bounds__(256) void precompute_P(
    const float* __restrict__ embed,
    const float* __restrict__ W1,
    float* __restrict__ P,
    int n_nodes)
{
    __shared__ float partial[2][16][64];   // [ng][node][unit] = 8 KB
    const int t    = threadIdx.x;
    const int lane = t & 63;
    const int wave = t >> 6;
    const int kh   = wave & 1;             // k-half this wave owns
    const int ng   = wave >> 1;            // node-group (16 nodes)
    const int node0 = blockIdx.x * 32 + ng * 16;

    // --- W half-row -> 64 VGPRs, pinned (prevents rematerialization) ---
    const int h   = lane & 31;
    const int tbl = lane >> 5;             // 0 = src half, 1 = dst half
    const float* wrow = W1 + (size_t)h * (2 * IN_FEATS) + tbl * IN_FEATS + kh * 64;
    float4 w[16];
#pragma unroll
    for (int i = 0; i < 16; ++i) {
        w[i] = *reinterpret_cast<const float4*>(wrow + i * 4);
        asm volatile("" : "+v"(w[i].x), "+v"(w[i].y), "+v"(w[i].z), "+v"(w[i].w));
    }

    const int last = (n_nodes > 0) ? (n_nodes - 1) : 0;

    // --- wave-uniform row offsets -> SGPRs (forces scalar-load path) ---
    int row_off[16];
#pragma unroll
    for (int j = 0; j < 16; ++j) {
        const int n = min(node0 + j, last);
        row_off[j] = __builtin_amdgcn_readfirstlane(n * IN_FEATS + kh * 64);
    }

    float acc[16];
#pragma unroll
    for (int j = 0; j < 16; ++j) acc[j] = 0.f;

    // --- K=64 dot products: 256 scalar loads + 1024 FMAs, fully unrolled ---
#pragma unroll
    for (int i = 0; i < 16; ++i) {
        const float4 wi = w[i];
#pragma unroll
        for (int j = 0; j < 16; ++j) {
            const float4 ev = *reinterpret_cast<const float4*>(embed + row_off[j] + i * 4);
            float a = acc[j];
            a = fmaf(ev.x, wi.x, a);
            a = fmaf(ev.y, wi.y, a);
            a = fmaf(ev.z, wi.z, a);
            a = fmaf(ev.w, wi.w, a);
            acc[j] = a;
        }
    }

    // --- combine k-halves: kh=0 -> LDS, kh=1 adds and stores ---
    if (kh == 0) {
#pragma unroll
        for (int j = 0; j < 16; ++j)
            partial[ng][j][lane] = acc[j];
    }
    __syncthreads();
    if (kh == 1) {
#pragma unroll
        for (int j = 0; j < 16; ++j) {
            const int n = node0 + j;
            if (n < n_nodes)
                P[(size_t)n * 64 + lane] = acc[j] + partial[ng][j][lane];
        }
    }
}

// ---------------------------------------------------------------------------
// Kernel 2: per-edge  logits = relu(P[s][0:32] + P[d][32:64] + b1) @ W2.T + b2
// One thread per edge; 16 float4 gathers from the 25.6 MB L2/L3-resident table.
// ---------------------------------------------------------------------------
__global__ __launch_bounds__(256) void edge_classify(
    const int* __restrict__ src,
    const int* __restrict__ dst,
    const float* __restrict__ P,
    const float* __restrict__ b1,
    const float* __restrict__ W2,
    const float* __restrict__ b2,
    float* __restrict__ out,
    int n_edges)
{
    const int e = blockIdx.x * 256 + threadIdx.x;
    if (e >= n_edges) return;
    const int s = src[e];
    const int d = dst[e];
    const float4* ps = reinterpret_cast<const float4*>(P + (size_t)s * 64);
    const float4* pd = reinterpret_cast<const float4*>(P + (size_t)d * 64 + 32);

    float4 a[8], b[8];
#pragma unroll
    for (int q = 0; q < 8; ++q) { a[q] = ps[q]; b[q] = pd[q]; }

    float l0 = b2[0], l1 = b2[1];
#pragma unroll
    for (int q = 0; q < 8; ++q) {
        const float va[4] = {a[q].x, a[q].y, a[q].z, a[q].w};
        const float vb[4] = {b[q].x, b[q].y, b[q].z, b[q].w};
#pragma unroll
        for (int j = 0; j < 4; ++j) {
            const int k = q * 4 + j;
            float hval = va[j] + vb[j] + b1[k];
            hval = fmaxf(hval, 0.f);
            l0 = fmaf(hval, W2[k], l0);
            l1 = fmaf(hval, W2[HIDDEN + k], l1);
        }
    }
    *reinterpret_cast<float2*>(out + (size_t)e * 2) = make_float2(l0, l1);
}

// ---------------------------------------------------------------------------
// Fallback (only if workspace too small): direct per-edge computation.
// ---------------------------------------------------------------------------
__global__ __launch_bounds__(256) void edge_direct(
    const int* __restrict__ src, const int* __restrict__ dst,
    const float* __restrict__ embed,
    const float* __restrict__ W1, const float* __restrict__ b1,
    const float* __restrict__ W2, const float* __restrict__ b2,
    float* __restrict__ out, int n_edges)
{
    const int e = blockIdx.x * 256 + threadIdx.x;
    if (e >= n_edges) return;
    const int s = src[e], d = dst[e];
    const float* se = embed + (size_t)s * IN_FEATS;
    const float* de = embed + (size_t)d * IN_FEATS;

    float acc[HIDDEN];
#pragma unroll
    for (int hh = 0; hh < HIDDEN; ++hh) acc[hh] = b1[hh];

    for (int c = 0; c < 4; ++c) {
        float es[32], ed[32];
#pragma unroll
        for (int q = 0; q < 8; ++q) {
            const float4 v = *reinterpret_cast<const float4*>(se + c * 32 + q * 4);
            es[q*4+0] = v.x; es[q*4+1] = v.y; es[q*4+2] = v.z; es[q*4+3] = v.w;
            const float4 u = *reinterpret_cast<const float4*>(de + c * 32 + q * 4);
            ed[q*4+0] = u.x; ed[q*4+1] = u.y; ed[q*4+2] = u.z; ed[q*4+3] = u.w;
        }
#pragma unroll
        for (int hh = 0; hh < HIDDEN; ++hh) {
            float acch = acc[hh];
#pragma unroll
            for (int k = 0; k < 32; ++k) {
                acch = fmaf(es[k], W1[hh * 256 + c * 32 + k], acch);
                acch = fmaf(ed[k], W1[hh * 256 + 128 + c * 32 + k], acch);
            }
            acc[hh] = acch;
        }
    }

    float l0 = b2[0], l1 = b2[1];
#pragma unroll
    for (int hh = 0; hh < HIDDEN; ++hh) {
        const float hv = fmaxf(acc[hh], 0.f);
        l0 = fmaf(hv, W2[hh], l0);
        l1 = fmaf(hv, W2[HIDDEN + hh], l1);
    }
    *reinterpret_cast<float2*>(out + (size_t)e * 2) = make_float2(l0, l1);
}

extern "C" void kernel_launch(void* const* d_in, const int* in_sizes, int n_in,
                              void* d_out, int out_size, void* d_ws, size_t ws_size,
                              hipStream_t stream)
{
    const int*   src = (const int*)d_in[0];
    const int*   dst = (const int*)d_in[1];
    const float* emb = (const float*)d_in[2];
    const float* W1  = (const float*)d_in[3];
    const float* b1  = (const float*)d_in[4];
    const float* W2  = (const float*)d_in[5];
    const float* b2  = (const float*)d_in[6];
    float* out = (float*)d_out;

    const int n_edges = in_sizes[0];
    const int n_nodes = in_sizes[2] / IN_FEATS;

    const size_t need = (size_t)n_nodes * 64 * sizeof(float);
    const int nb_edges = (n_edges + 255) / 256;

    if (ws_size >= need) {
        float* P = (float*)d_ws;
        const int nb_nodes = (n_nodes + 31) / 32;   // 32-node tiles
        precompute_P<<<nb_nodes, 256, 0, stream>>>(emb, W1, P, n_nodes);
        edge_classify<<<nb_edges, 256, 0, stream>>>(src, dst, P, b1, W2, b2, out, n_edges);
    } else {
        edge_direct<<<nb_edges, 256, 0, stream>>>(src, dst, emb, W1, b1, W2, b2, out, n_edges);
    }
}

// Round 6
// 82.902 us; speedup vs baseline: 4.4860x; 1.0888x over previous
//
#include <hip/hip_runtime.h>

#define IN_FEATS 128
#define HIDDEN 32

// ---------------------------------------------------------------------------
// Kernel 0: pre-pack W1 into Wp so the main loop's wave-uniform W reads are
// contiguous 64-float blocks (compiler merges them into s_load_dwordx16).
// Wp[(((kh*16 + kcg)*4 + ug)*16 + ui)*4 + m] = W_t[k][u]
//   where u = ug*16+ui, k = kh*64 + kcg*4 + m,
//         W_t[k][u] = W1[u&31][(u>>5)*128 + k]   (u<32: Ws, u>=32: Wd)
// ---------------------------------------------------------------------------
__global__ __launch_bounds__(256) void pack_W(const float* __restrict__ W1,
                                              float* __restrict__ Wp)
{
    const int i = blockIdx.x * 256 + threadIdx.x;   // 0..8191
    if (i >= 2 * IN_FEATS * 2 * HIDDEN) return;
    const int m   = i & 3;
    const int ui  = (i >> 2) & 15;
    const int ug  = (i >> 6) & 3;
    const int kcg = (i >> 8) & 15;
    const int kh  = (i >> 12) & 1;
    const int u   = ug * 16 + ui;
    const int k   = kh * 64 + kcg * 4 + m;
    Wp[i] = W1[(u & 31) * (2 * IN_FEATS) + (u >> 5) * IN_FEATS + k];
}

// ---------------------------------------------------------------------------
// Kernel 1: P[n][0:32] = embed[n] @ W1s.T ; P[n][32:64] = embed[n] @ W1d.T
//
// Block = 128 threads = 2 waves (wave = kh k-half); tile = 64 nodes.
// lane = node: e-row half in VGPRs via per-lane global_load_dwordx4 bursts
//              (8 loads = one full 128B line per lane, consumed immediately).
// W = wave-uniform -> SGPRs via readfirstlane'd offsets into packed Wp;
//     inner loop is v_fmac_f32 (VGPR e) x (SGPR w) -> 64 acc VGPRs.
// R5 lesson: 256 narrow dependent s_loads serialized on SMEM latency; here
// W loads are 4x dwordx16 per 512 VALU-cycles -- issue-trivial, wave-hidden.
// kh halves combine in LDS (stride-65 rows: bank = (n+u)%32, 2-way = free),
// then all threads do a fully-coalesced float4 store pass.
// ---------------------------------------------------------------------------
__global__ __launch_bounds__(128, 4) void precompute_P(
    const float* __restrict__ embed,
    const float* __restrict__ Wp,
    float* __restrict__ P,
    int n_nodes)
{
    __shared__ float buf[64][65];                 // 16.6 KB
    const int t    = threadIdx.x;
    const int lane = t & 63;
    const int kh   = t >> 6;                      // wave 0/1 = k-half
    const int node0 = blockIdx.x * 64;
    const int last  = n_nodes - 1;
    const int n     = min(node0 + lane, last);
    const float* erow = embed + (size_t)n * IN_FEATS + kh * 64;

    float acc[64];
#pragma unroll
    for (int u = 0; u < 64; ++u) acc[u] = 0.f;

#pragma unroll 1
    for (int half = 0; half < 2; ++half) {        // two 128B halves of the row
        float4 e[8];
#pragma unroll
        for (int q = 0; q < 8; ++q)
            e[q] = *reinterpret_cast<const float4*>(erow + half * 32 + q * 4);

#pragma unroll
        for (int kc = 0; kc < 8; ++kc) {
            // wave-uniform offset -> scalar loads of 256B packed W block
            const int wkoff = __builtin_amdgcn_readfirstlane(
                kh * 4096 + (half * 8 + kc) * 256);
            const float* wk = Wp + wkoff;
            const float4 ev = e[kc];
#pragma unroll
            for (int ug = 0; ug < 4; ++ug) {
#pragma unroll
                for (int ui = 0; ui < 16; ++ui) {
                    const float w0 = wk[ug * 64 + ui * 4 + 0];
                    const float w1 = wk[ug * 64 + ui * 4 + 1];
                    const float w2 = wk[ug * 64 + ui * 4 + 2];
                    const float w3 = wk[ug * 64 + ui * 4 + 3];
                    float a = acc[ug * 16 + ui];
                    a = fmaf(ev.x, w0, a);
                    a = fmaf(ev.y, w1, a);
                    a = fmaf(ev.z, w2, a);
                    a = fmaf(ev.w, w3, a);
                    acc[ug * 16 + ui] = a;
                }
            }
        }
    }

    // --- combine k-halves in LDS (stride 65: bank=(n+u)%32, 2-way = free) ---
    if (kh == 0) {
#pragma unroll
        for (int u = 0; u < 64; ++u) buf[lane][u] = acc[u];
    }
    __syncthreads();
    if (kh == 1) {
#pragma unroll
        for (int u = 0; u < 64; ++u) buf[lane][u] += acc[u];
    }
    __syncthreads();

    // --- cooperative fully-coalesced store: 64 nodes x 64 floats ---
#pragma unroll
    for (int j = 0; j < 8; ++j) {
        const int f4 = j * 128 + t;               // float4 index in tile
        const int nl = f4 >> 4;                   // local node
        const int w4 = (f4 & 15) * 4;             // word offset in P row
        const int n2 = node0 + nl;
        if (n2 < n_nodes) {
            float4 v;
            v.x = buf[nl][w4 + 0];
            v.y = buf[nl][w4 + 1];
            v.z = buf[nl][w4 + 2];
            v.w = buf[nl][w4 + 3];
            *reinterpret_cast<float4*>(P + (size_t)n2 * 64 + w4) = v;
        }
    }
}

// ---------------------------------------------------------------------------
// Kernel 2: per-edge  logits = relu(P[s][0:32] + P[d][32:64] + b1) @ W2.T + b2
// One thread per edge; 16 float4 gathers from the 25.6 MB L2/L3-resident table.
// ---------------------------------------------------------------------------
__global__ __launch_bounds__(256) void edge_classify(
    const int* __restrict__ src,
    const int* __restrict__ dst,
    const float* __restrict__ P,
    const float* __restrict__ b1,
    const float* __restrict__ W2,
    const float* __restrict__ b2,
    float* __restrict__ out,
    int n_edges)
{
    const int e = blockIdx.x * 256 + threadIdx.x;
    if (e >= n_edges) return;
    const int s = src[e];
    const int d = dst[e];
    const float4* ps = reinterpret_cast<const float4*>(P + (size_t)s * 64);
    const float4* pd = reinterpret_cast<const float4*>(P + (size_t)d * 64 + 32);

    float4 a[8], b[8];
#pragma unroll
    for (int q = 0; q < 8; ++q) { a[q] = ps[q]; b[q] = pd[q]; }

    float l0 = b2[0], l1 = b2[1];
#pragma unroll
    for (int q = 0; q < 8; ++q) {
        const float va[4] = {a[q].x, a[q].y, a[q].z, a[q].w};
        const float vb[4] = {b[q].x, b[q].y, b[q].z, b[q].w};
#pragma unroll
        for (int j = 0; j < 4; ++j) {
            const int k = q * 4 + j;
            float hval = va[j] + vb[j] + b1[k];
            hval = fmaxf(hval, 0.f);
            l0 = fmaf(hval, W2[k], l0);
            l1 = fmaf(hval, W2[HIDDEN + k], l1);
        }
    }
    *reinterpret_cast<float2*>(out + (size_t)e * 2) = make_float2(l0, l1);
}

// ---------------------------------------------------------------------------
// Fallback (only if workspace too small): direct per-edge computation.
// ---------------------------------------------------------------------------
__global__ __launch_bounds__(256) void edge_direct(
    const int* __restrict__ src, const int* __restrict__ dst,
    const float* __restrict__ embed,
    const float* __restrict__ W1, const float* __restrict__ b1,
    const float* __restrict__ W2, const float* __restrict__ b2,
    float* __restrict__ out, int n_edges)
{
    const int e = blockIdx.x * 256 + threadIdx.x;
    if (e >= n_edges) return;
    const int s = src[e], d = dst[e];
    const float* se = embed + (size_t)s * IN_FEATS;
    const float* de = embed + (size_t)d * IN_FEATS;

    float acc[HIDDEN];
#pragma unroll
    for (int hh = 0; hh < HIDDEN; ++hh) acc[hh] = b1[hh];

    for (int c = 0; c < 4; ++c) {
        float es[32], ed[32];
#pragma unroll
        for (int q = 0; q < 8; ++q) {
            const float4 v = *reinterpret_cast<const float4*>(se + c * 32 + q * 4);
            es[q*4+0] = v.x; es[q*4+1] = v.y; es[q*4+2] = v.z; es[q*4+3] = v.w;
            const float4 u = *reinterpret_cast<const float4*>(de + c * 32 + q * 4);
            ed[q*4+0] = u.x; ed[q*4+1] = u.y; ed[q*4+2] = u.z; ed[q*4+3] = u.w;
        }
#pragma unroll
        for (int hh = 0; hh < HIDDEN; ++hh) {
            float acch = acc[hh];
#pragma unroll
            for (int k = 0; k < 32; ++k) {
                acch = fmaf(es[k], W1[hh * 256 + c * 32 + k], acch);
                acch = fmaf(ed[k], W1[hh * 256 + 128 + c * 32 + k], acch);
            }
            acc[hh] = acch;
        }
    }

    float l0 = b2[0], l1 = b2[1];
#pragma unroll
    for (int hh = 0; hh < HIDDEN; ++hh) {
        const float hv = fmaxf(acc[hh], 0.f);
        l0 = fmaf(hv, W2[hh], l0);
        l1 = fmaf(hv, W2[HIDDEN + hh], l1);
    }
    *reinterpret_cast<float2*>(out + (size_t)e * 2) = make_float2(l0, l1);
}

extern "C" void kernel_launch(void* const* d_in, const int* in_sizes, int n_in,
                              void* d_out, int out_size, void* d_ws, size_t ws_size,
                              hipStream_t stream)
{
    const int*   src = (const int*)d_in[0];
    const int*   dst = (const int*)d_in[1];
    const float* emb = (const float*)d_in[2];
    const float* W1  = (const float*)d_in[3];
    const float* b1  = (const float*)d_in[4];
    const float* W2  = (const float*)d_in[5];
    const float* b2  = (const float*)d_in[6];
    float* out = (float*)d_out;

    const int n_edges = in_sizes[0];
    const int n_nodes = in_sizes[2] / IN_FEATS;

    const size_t p_bytes  = (size_t)n_nodes * 64 * sizeof(float);
    const size_t wp_bytes = (size_t)2 * IN_FEATS * 2 * HIDDEN * sizeof(float);
    const int nb_edges = (n_edges + 255) / 256;

    if (ws_size >= p_bytes + wp_bytes) {
        float* P  = (float*)d_ws;
        float* Wp = (float*)((char*)d_ws + p_bytes);
        pack_W<<<(2 * IN_FEATS * 2 * HIDDEN + 255) / 256, 256, 0, stream>>>(W1, Wp);
        const int nb_nodes = (n_nodes + 63) / 64;   // 64-node tiles
        precompute_P<<<nb_nodes, 128, 0, stream>>>(emb, Wp, P, n_nodes);
        edge_classify<<<nb_edges, 256, 0, stream>>>(src, dst, P, b1, W2, b2, out, n_edges);
    } else {
        edge_direct<<<nb_edges, 256, 0, stream>>>(src, dst, emb, W1, b1, W2, b2, out, n_edges);
    }
}

// Round 7
// 60.182 us; speedup vs baseline: 6.1795x; 1.3775x over previous
//
#include <hip/hip_runtime.h>

#define IN_FEATS 128
#define HIDDEN 32

typedef short v8s __attribute__((ext_vector_type(8)));
typedef float v4f __attribute__((ext_vector_type(4)));

__device__ __forceinline__ unsigned short f2bf(float x) {
    union { float f; unsigned int u; } v; v.f = x;
    const unsigned int r = v.u + 0x7fffu + ((v.u >> 16) & 1u);   // RNE
    return (unsigned short)(r >> 16);
}
__device__ __forceinline__ float bf2f(unsigned short b) {
    union { float f; unsigned int u; } v; v.u = ((unsigned int)b) << 16;
    return v.f;
}

// ---------------------------------------------------------------------------
// Kernel 0: pack W1 into per-lane MFMA B-fragments, split bf16 hi/lo.
// Fragment slot i = ((nb*4 + ks)*64 + lane)*8 + j  holds  B[k][u]
//   u = nb*16 + (lane&15),  k = ks*32 + ((lane>>4)&3)*8 + j
//   B[k][u] = W1[u&31][(u>>5)*128 + k]   (u<32: Ws half, u>=32: Wd half)
// A uses the identical (group,j)->k map, so any common k-permutation of the
// hardware layout cancels in the MFMA K-sum.
// ---------------------------------------------------------------------------
__global__ __launch_bounds__(256) void pack_W_frags(
    const float* __restrict__ W1,
    unsigned short* __restrict__ Bhi,
    unsigned short* __restrict__ Blo)
{
    const int i = blockIdx.x * 256 + threadIdx.x;   // 0..8191
    if (i >= 4 * 4 * 64 * 8) return;
    const int j    = i & 7;
    const int lane = (i >> 3) & 63;
    const int ks   = (i >> 9) & 3;
    const int nb   = i >> 11;
    const int u = nb * 16 + (lane & 15);
    const int k = ks * 32 + ((lane >> 4) & 3) * 8 + j;
    const float w = W1[(u & 31) * (2 * IN_FEATS) + (u >> 5) * IN_FEATS + k];
    const unsigned short hi = f2bf(w);
    Bhi[i] = hi;
    Blo[i] = f2bf(w - bf2f(hi));
}

// ---------------------------------------------------------------------------
// Kernel 1: P[n][0:64] = embed[n] @ [W1s|W1d].T  via split-bf16 MFMA.
// Wave = 16 nodes x 64 units x K=128: 4 N-blocks x 4 K-steps x 3 MFMAs = 48.
// A: lane holds rows node0+(lane&15), k = ks*32 + (lane>>4)*8 + j (2 float4
//    global loads per k-step, each 128B embed line consumed exactly once).
// C/D (HW-verified): unit col = lane&15, node row = (lane>>4)*4 + reg.
// No LDS, no barriers; ~90 VGPR -> 4 waves/SIMD.
// ---------------------------------------------------------------------------
__global__ __launch_bounds__(256, 4) void precompute_P_mfma(
    const float* __restrict__ embed,
    const unsigned short* __restrict__ Bhi,
    const unsigned short* __restrict__ Blo,
    float* __restrict__ P,
    int n_nodes)
{
    const int t    = threadIdx.x;
    const int lane = t & 63;
    const int wave = t >> 6;
    const int node0 = blockIdx.x * 64 + wave * 16;
    if (node0 >= n_nodes) return;                  // wave-uniform, no barriers
    const int last = n_nodes - 1;
    const int row  = min(node0 + (lane & 15), last);
    const int grp  = lane >> 4;

    // --- A fragments (hi/lo) for the 4 K-steps ---
    v8s ahi[4], alo[4];
#pragma unroll
    for (int ks = 0; ks < 4; ++ks) {
        const float* ap = embed + (size_t)row * IN_FEATS + ks * 32 + grp * 8;
        const float4 x0 = *reinterpret_cast<const float4*>(ap);
        const float4 x1 = *reinterpret_cast<const float4*>(ap + 4);
        const float xs[8] = {x0.x, x0.y, x0.z, x0.w, x1.x, x1.y, x1.z, x1.w};
        v8s h, l;
#pragma unroll
        for (int j = 0; j < 8; ++j) {
            const unsigned short hb = f2bf(xs[j]);
            h[j] = (short)hb;
            l[j] = (short)f2bf(xs[j] - bf2f(hb));
        }
        ahi[ks] = h;
        alo[ks] = l;
    }

    // --- 4 N-blocks of 16 units ---
#pragma unroll
    for (int nb = 0; nb < 4; ++nb) {
        v8s bhi[4], blo[4];
#pragma unroll
        for (int ks = 0; ks < 4; ++ks) {
            const int fi = ((nb * 4 + ks) * 64 + lane) * 8;
            bhi[ks] = *reinterpret_cast<const v8s*>(Bhi + fi);
            blo[ks] = *reinterpret_cast<const v8s*>(Blo + fi);
        }
        v4f acc = {0.f, 0.f, 0.f, 0.f};
#pragma unroll
        for (int ks = 0; ks < 4; ++ks) {
            acc = __builtin_amdgcn_mfma_f32_16x16x32_bf16(ahi[ks], bhi[ks], acc, 0, 0, 0);
            acc = __builtin_amdgcn_mfma_f32_16x16x32_bf16(ahi[ks], blo[ks], acc, 0, 0, 0);
            acc = __builtin_amdgcn_mfma_f32_16x16x32_bf16(alo[ks], bhi[ks], acc, 0, 0, 0);
        }
        const int u = nb * 16 + (lane & 15);
#pragma unroll
        for (int r = 0; r < 4; ++r) {
            const int n = node0 + grp * 4 + r;
            if (n < n_nodes)
                P[(size_t)n * 64 + u] = acc[r];
        }
    }
}

// ---------------------------------------------------------------------------
// Kernel 2: per-edge  logits = relu(P[s][0:32] + P[d][32:64] + b1) @ W2.T + b2
// One thread per edge; 16 float4 gathers from the 25.6 MB L2/L3-resident table.
// ---------------------------------------------------------------------------
__global__ __launch_bounds__(256) void edge_classify(
    const int* __restrict__ src,
    const int* __restrict__ dst,
    const float* __restrict__ P,
    const float* __restrict__ b1,
    const float* __restrict__ W2,
    const float* __restrict__ b2,
    float* __restrict__ out,
    int n_edges)
{
    const int e = blockIdx.x * 256 + threadIdx.x;
    if (e >= n_edges) return;
    const int s = src[e];
    const int d = dst[e];
    const float4* ps = reinterpret_cast<const float4*>(P + (size_t)s * 64);
    const float4* pd = reinterpret_cast<const float4*>(P + (size_t)d * 64 + 32);

    float4 a[8], b[8];
#pragma unroll
    for (int q = 0; q < 8; ++q) { a[q] = ps[q]; b[q] = pd[q]; }

    float l0 = b2[0], l1 = b2[1];
#pragma unroll
    for (int q = 0; q < 8; ++q) {
        const float va[4] = {a[q].x, a[q].y, a[q].z, a[q].w};
        const float vb[4] = {b[q].x, b[q].y, b[q].z, b[q].w};
#pragma unroll
        for (int j = 0; j < 4; ++j) {
            const int k = q * 4 + j;
            float hval = va[j] + vb[j] + b1[k];
            hval = fmaxf(hval, 0.f);
            l0 = fmaf(hval, W2[k], l0);
            l1 = fmaf(hval, W2[HIDDEN + k], l1);
        }
    }
    *reinterpret_cast<float2*>(out + (size_t)e * 2) = make_float2(l0, l1);
}

// ---------------------------------------------------------------------------
// Fallback (only if workspace too small): direct per-edge computation.
// ---------------------------------------------------------------------------
__global__ __launch_bounds__(256) void edge_direct(
    const int* __restrict__ src, const int* __restrict__ dst,
    const float* __restrict__ embed,
    const float* __restrict__ W1, const float* __restrict__ b1,
    const float* __restrict__ W2, const float* __restrict__ b2,
    float* __restrict__ out, int n_edges)
{
    const int e = blockIdx.x * 256 + threadIdx.x;
    if (e >= n_edges) return;
    const int s = src[e], d = dst[e];
    const float* se = embed + (size_t)s * IN_FEATS;
    const float* de = embed + (size_t)d * IN_FEATS;

    float acc[HIDDEN];
#pragma unroll
    for (int hh = 0; hh < HIDDEN; ++hh) acc[hh] = b1[hh];

    for (int c = 0; c < 4; ++c) {
        float es[32], ed[32];
#pragma unroll
        for (int q = 0; q < 8; ++q) {
            const float4 v = *reinterpret_cast<const float4*>(se + c * 32 + q * 4);
            es[q*4+0] = v.x; es[q*4+1] = v.y; es[q*4+2] = v.z; es[q*4+3] = v.w;
            const float4 u = *reinterpret_cast<const float4*>(de + c * 32 + q * 4);
            ed[q*4+0] = u.x; ed[q*4+1] = u.y; ed[q*4+2] = u.z; ed[q*4+3] = u.w;
        }
#pragma unroll
        for (int hh = 0; hh < HIDDEN; ++hh) {
            float acch = acc[hh];
#pragma unroll
            for (int k = 0; k < 32; ++k) {
                acch = fmaf(es[k], W1[hh * 256 + c * 32 + k], acch);
                acch = fmaf(ed[k], W1[hh * 256 + 128 + c * 32 + k], acch);
            }
            acc[hh] = acch;
        }
    }

    float l0 = b2[0], l1 = b2[1];
#pragma unroll
    for (int hh = 0; hh < HIDDEN; ++hh) {
        const float hv = fmaxf(acc[hh], 0.f);
        l0 = fmaf(hv, W2[hh], l0);
        l1 = fmaf(hv, W2[HIDDEN + hh], l1);
    }
    *reinterpret_cast<float2*>(out + (size_t)e * 2) = make_float2(l0, l1);
}

extern "C" void kernel_launch(void* const* d_in, const int* in_sizes, int n_in,
                              void* d_out, int out_size, void* d_ws, size_t ws_size,
                              hipStream_t stream)
{
    const int*   src = (const int*)d_in[0];
    const int*   dst = (const int*)d_in[1];
    const float* emb = (const float*)d_in[2];
    const float* W1  = (const float*)d_in[3];
    const float* b1  = (const float*)d_in[4];
    const float* W2  = (const float*)d_in[5];
    const float* b2  = (const float*)d_in[6];
    float* out = (float*)d_out;

    const int n_edges = in_sizes[0];
    const int n_nodes = in_sizes[2] / IN_FEATS;

    const size_t p_bytes = (size_t)n_nodes * 64 * sizeof(float);
    const size_t b_elems = 4 * 4 * 64 * 8;            // 8192 fragment slots
    const size_t need = p_bytes + 2 * b_elems * sizeof(unsigned short);
    const int nb_edges = (n_edges + 255) / 256;

    if (ws_size >= need) {
        float* P = (float*)d_ws;
        unsigned short* Bhi = (unsigned short*)((char*)d_ws + p_bytes);
        unsigned short* Blo = Bhi + b_elems;
        pack_W_frags<<<(int)((b_elems + 255) / 256), 256, 0, stream>>>(W1, Bhi, Blo);
        const int nb_nodes = (n_nodes + 63) / 64;     // 64 nodes per block
        precompute_P_mfma<<<nb_nodes, 256, 0, stream>>>(emb, Bhi, Blo, P, n_nodes);
        edge_classify<<<nb_edges, 256, 0, stream>>>(src, dst, P, b1, W2, b2, out, n_edges);
    } else {
        edge_direct<<<nb_edges, 256, 0, stream>>>(src, dst, emb, W1, b1, W2, b2, out, n_edges);
    }
}

// Round 8
// 46.528 us; speedup vs baseline: 7.9930x; 1.2935x over previous
//
#include <hip/hip_runtime.h>

#define IN_FEATS 128
#define HIDDEN 32

typedef short v8s __attribute__((ext_vector_type(8)));
typedef unsigned short u16x8 __attribute__((ext_vector_type(8)));
typedef float v4f __attribute__((ext_vector_type(4)));

__device__ __forceinline__ unsigned short f2bf(float x) {
    union { float f; unsigned int u; } v; v.f = x;
    const unsigned int r = v.u + 0x7fffu + ((v.u >> 16) & 1u);   // RNE
    return (unsigned short)(r >> 16);
}
__device__ __forceinline__ float bf2f(unsigned short b) {
    union { float f; unsigned int u; } v; v.u = ((unsigned int)b) << 16;
    return v.f;
}

// ---------------------------------------------------------------------------
// Kernel 0: pack W1 into per-lane MFMA B-fragments, split bf16 hi/lo.
// Fragment slot i = ((nb*4 + ks)*64 + lane)*8 + j  holds  B[k][u]
//   u = nb*16 + (lane&15),  k = ks*32 + ((lane>>4)&3)*8 + j
//   B[k][u] = W1[u&31][(u>>5)*128 + k]   (u<32: Ws half, u>=32: Wd half)
// A uses the identical (group,j)->k map, so any common k-permutation of the
// hardware layout cancels in the MFMA K-sum.
// ---------------------------------------------------------------------------
__global__ __launch_bounds__(256) void pack_W_frags(
    const float* __restrict__ W1,
    unsigned short* __restrict__ Bhi,
    unsigned short* __restrict__ Blo)
{
    const int i = blockIdx.x * 256 + threadIdx.x;   // 0..8191
    if (i >= 4 * 4 * 64 * 8) return;
    const int j    = i & 7;
    const int lane = (i >> 3) & 63;
    const int ks   = (i >> 9) & 3;
    const int nb   = i >> 11;
    const int u = nb * 16 + (lane & 15);
    const int k = ks * 32 + ((lane >> 4) & 3) * 8 + j;
    const float w = W1[(u & 31) * (2 * IN_FEATS) + (u >> 5) * IN_FEATS + k];
    const unsigned short hi = f2bf(w);
    Bhi[i] = hi;
    Blo[i] = f2bf(w - bf2f(hi));
}

// ---------------------------------------------------------------------------
// Kernel 1: P[n][0:64] = embed[n] @ [W1s|W1d].T  via split-bf16 MFMA,
// output stored as bf16 (halves write traffic AND edge-phase gather bytes).
// Wave = 16 nodes x 64 units x K=128: 4 N-blocks x 4 K-steps x 3 MFMAs = 48.
// C/D (HW-verified): unit col = lane&15, node row = (lane>>4)*4 + reg.
// No LDS, no barriers.
// ---------------------------------------------------------------------------
__global__ __launch_bounds__(256, 4) void precompute_P_mfma(
    const float* __restrict__ embed,
    const unsigned short* __restrict__ Bhi,
    const unsigned short* __restrict__ Blo,
    unsigned short* __restrict__ P,        // bf16 [n][64]
    int n_nodes)
{
    const int t    = threadIdx.x;
    const int lane = t & 63;
    const int wave = t >> 6;
    const int node0 = blockIdx.x * 64 + wave * 16;
    if (node0 >= n_nodes) return;                  // wave-uniform, no barriers
    const int last = n_nodes - 1;
    const int row  = min(node0 + (lane & 15), last);
    const int grp  = lane >> 4;

    // --- A fragments (hi/lo) for the 4 K-steps ---
    v8s ahi[4], alo[4];
#pragma unroll
    for (int ks = 0; ks < 4; ++ks) {
        const float* ap = embed + (size_t)row * IN_FEATS + ks * 32 + grp * 8;
        const float4 x0 = *reinterpret_cast<const float4*>(ap);
        const float4 x1 = *reinterpret_cast<const float4*>(ap + 4);
        const float xs[8] = {x0.x, x0.y, x0.z, x0.w, x1.x, x1.y, x1.z, x1.w};
        v8s h, l;
#pragma unroll
        for (int j = 0; j < 8; ++j) {
            const unsigned short hb = f2bf(xs[j]);
            h[j] = (short)hb;
            l[j] = (short)f2bf(xs[j] - bf2f(hb));
        }
        ahi[ks] = h;
        alo[ks] = l;
    }

    // --- 4 N-blocks of 16 units ---
#pragma unroll
    for (int nb = 0; nb < 4; ++nb) {
        v8s bhi[4], blo[4];
#pragma unroll
        for (int ks = 0; ks < 4; ++ks) {
            const int fi = ((nb * 4 + ks) * 64 + lane) * 8;
            bhi[ks] = *reinterpret_cast<const v8s*>(Bhi + fi);
            blo[ks] = *reinterpret_cast<const v8s*>(Blo + fi);
        }
        v4f acc = {0.f, 0.f, 0.f, 0.f};
#pragma unroll
        for (int ks = 0; ks < 4; ++ks) {
            acc = __builtin_amdgcn_mfma_f32_16x16x32_bf16(ahi[ks], bhi[ks], acc, 0, 0, 0);
            acc = __builtin_amdgcn_mfma_f32_16x16x32_bf16(ahi[ks], blo[ks], acc, 0, 0, 0);
            acc = __builtin_amdgcn_mfma_f32_16x16x32_bf16(alo[ks], bhi[ks], acc, 0, 0, 0);
        }
        const int u = nb * 16 + (lane & 15);
#pragma unroll
        for (int r = 0; r < 4; ++r) {
            const int n = node0 + grp * 4 + r;
            if (n < n_nodes)
                P[(size_t)n * 64 + u] = f2bf(acc[r]);
        }
    }
}

// ---------------------------------------------------------------------------
// Kernel 2: per-edge  logits = relu(Ps[s] + Pd[d] + b1) @ W2.T + b2
// 4 lanes per edge: lane q owns units [8q, 8q+8). One 16 B bf16 gather per
// row-half per lane -> each gather instruction touches 16 rows (not 64),
// ~4x fewer L1 transactions. Quad shfl_xor reduction for the 2 logits.
// ---------------------------------------------------------------------------
__global__ __launch_bounds__(256) void edge_classify_bf16(
    const int* __restrict__ src,
    const int* __restrict__ dst,
    const unsigned short* __restrict__ P,   // bf16 [n][64]
    const float* __restrict__ b1,
    const float* __restrict__ W2,
    const float* __restrict__ b2,
    float* __restrict__ out,
    int n_edges)
{
    const int t = threadIdx.x;
    const int e = blockIdx.x * 64 + (t >> 2);   // 64 edges per 256-thread block
    if (e >= n_edges) return;
    const int q = t & 3;                        // quad lane: units 8q..8q+7
    const int s = src[e];
    const int d = dst[e];

    const u16x8 ps = *reinterpret_cast<const u16x8*>(P + (size_t)s * 64 + q * 8);
    const u16x8 pd = *reinterpret_cast<const u16x8*>(P + (size_t)d * 64 + 32 + q * 8);

    const float4 b1a = *reinterpret_cast<const float4*>(b1 + q * 8);
    const float4 b1b = *reinterpret_cast<const float4*>(b1 + q * 8 + 4);
    const float4 w0a = *reinterpret_cast<const float4*>(W2 + q * 8);
    const float4 w0b = *reinterpret_cast<const float4*>(W2 + q * 8 + 4);
    const float4 w1a = *reinterpret_cast<const float4*>(W2 + HIDDEN + q * 8);
    const float4 w1b = *reinterpret_cast<const float4*>(W2 + HIDDEN + q * 8 + 4);
    const float bb1[8] = {b1a.x, b1a.y, b1a.z, b1a.w, b1b.x, b1b.y, b1b.z, b1b.w};
    const float ww0[8] = {w0a.x, w0a.y, w0a.z, w0a.w, w0b.x, w0b.y, w0b.z, w0b.w};
    const float ww1[8] = {w1a.x, w1a.y, w1a.z, w1a.w, w1b.x, w1b.y, w1b.z, w1b.w};

    float l0 = 0.f, l1 = 0.f;
#pragma unroll
    for (int j = 0; j < 8; ++j) {
        float h = bf2f(ps[j]) + bf2f(pd[j]) + bb1[j];
        h = fmaxf(h, 0.f);
        l0 = fmaf(h, ww0[j], l0);
        l1 = fmaf(h, ww1[j], l1);
    }
    // quad reduction (lanes 4k..4k+3)
    l0 += __shfl_xor(l0, 1);
    l0 += __shfl_xor(l0, 2);
    l1 += __shfl_xor(l1, 1);
    l1 += __shfl_xor(l1, 2);
    if (q == 0)
        *reinterpret_cast<float2*>(out + (size_t)e * 2) =
            make_float2(l0 + b2[0], l1 + b2[1]);
}

// ---------------------------------------------------------------------------
// Fallback (only if workspace too small): direct per-edge computation.
// ---------------------------------------------------------------------------
__global__ __launch_bounds__(256) void edge_direct(
    const int* __restrict__ src, const int* __restrict__ dst,
    const float* __restrict__ embed,
    const float* __restrict__ W1, const float* __restrict__ b1,
    const float* __restrict__ W2, const float* __restrict__ b2,
    float* __restrict__ out, int n_edges)
{
    const int e = blockIdx.x * 256 + threadIdx.x;
    if (e >= n_edges) return;
    const int s = src[e], d = dst[e];
    const float* se = embed + (size_t)s * IN_FEATS;
    const float* de = embed + (size_t)d * IN_FEATS;

    float acc[HIDDEN];
#pragma unroll
    for (int hh = 0; hh < HIDDEN; ++hh) acc[hh] = b1[hh];

    for (int c = 0; c < 4; ++c) {
        float es[32], ed[32];
#pragma unroll
        for (int q = 0; q < 8; ++q) {
            const float4 v = *reinterpret_cast<const float4*>(se + c * 32 + q * 4);
            es[q*4+0] = v.x; es[q*4+1] = v.y; es[q*4+2] = v.z; es[q*4+3] = v.w;
            const float4 u = *reinterpret_cast<const float4*>(de + c * 32 + q * 4);
            ed[q*4+0] = u.x; ed[q*4+1] = u.y; ed[q*4+2] = u.z; ed[q*4+3] = u.w;
        }
#pragma unroll
        for (int hh = 0; hh < HIDDEN; ++hh) {
            float acch = acc[hh];
#pragma unroll
            for (int k = 0; k < 32; ++k) {
                acch = fmaf(es[k], W1[hh * 256 + c * 32 + k], acch);
                acch = fmaf(ed[k], W1[hh * 256 + 128 + c * 32 + k], acch);
            }
            acc[hh] = acch;
        }
    }

    float l0 = b2[0], l1 = b2[1];
#pragma unroll
    for (int hh = 0; hh < HIDDEN; ++hh) {
        const float hv = fmaxf(acc[hh], 0.f);
        l0 = fmaf(hv, W2[hh], l0);
        l1 = fmaf(hv, W2[HIDDEN + hh], l1);
    }
    *reinterpret_cast<float2*>(out + (size_t)e * 2) = make_float2(l0, l1);
}

extern "C" void kernel_launch(void* const* d_in, const int* in_sizes, int n_in,
                              void* d_out, int out_size, void* d_ws, size_t ws_size,
                              hipStream_t stream)
{
    const int*   src = (const int*)d_in[0];
    const int*   dst = (const int*)d_in[1];
    const float* emb = (const float*)d_in[2];
    const float* W1  = (const float*)d_in[3];
    const float* b1  = (const float*)d_in[4];
    const float* W2  = (const float*)d_in[5];
    const float* b2  = (const float*)d_in[6];
    float* out = (float*)d_out;

    const int n_edges = in_sizes[0];
    const int n_nodes = in_sizes[2] / IN_FEATS;

    const size_t p_bytes = (size_t)n_nodes * 64 * sizeof(unsigned short); // bf16 P
    const size_t b_elems = 4 * 4 * 64 * 8;            // 8192 fragment slots
    const size_t need = p_bytes + 2 * b_elems * sizeof(unsigned short);

    if (ws_size >= need && (p_bytes & 15) == 0) {
        unsigned short* P   = (unsigned short*)d_ws;
        unsigned short* Bhi = (unsigned short*)((char*)d_ws + p_bytes);
        unsigned short* Blo = Bhi + b_elems;
        pack_W_frags<<<(int)((b_elems + 255) / 256), 256, 0, stream>>>(W1, Bhi, Blo);
        const int nb_nodes = (n_nodes + 63) / 64;     // 64 nodes per block
        precompute_P_mfma<<<nb_nodes, 256, 0, stream>>>(emb, Bhi, Blo, P, n_nodes);
        const int nb_edges4 = (n_edges + 63) / 64;    // 64 edges per block
        edge_classify_bf16<<<nb_edges4, 256, 0, stream>>>(src, dst, P, b1, W2, b2, out, n_edges);
    } else {
        const int nb_edges = (n_edges + 255) / 256;
        edge_direct<<<nb_edges, 256, 0, stream>>>(src, dst, emb, W1, b1, W2, b2, out, n_edges);
    }
}